// Round 6
// baseline (186.017 us; speedup 1.0000x reference)
//
#include <hip/hip_runtime.h>
#include <hip/hip_bf16.h>

typedef unsigned short u16;
typedef unsigned int u32;
typedef __bf16 bf16x8 __attribute__((ext_vector_type(8)));
typedef float f32x4 __attribute__((ext_vector_type(4)));
typedef u16 u16x8 __attribute__((ext_vector_type(8)));
typedef u16 u16x4 __attribute__((ext_vector_type(4)));

#define NB 4
#define SEQ 2048
#define EMB 1024
#define NHEAD 16
#define DHEAD 64
#define MTOT (NB*SEQ)   // 8192

static __device__ __forceinline__ u16 f2bf(float f) {
  union { __bf16 h; u16 u; } cv;
  cv.h = (__bf16)f;
  return cv.u;
}

static __device__ __forceinline__ float fexp2(float x) {
  float r;
  asm("v_exp_f32 %0, %1" : "=v"(r) : "v"(x));   // exp2, 1 instr, exp2(-inf)=0
  return r;
}

static __device__ __forceinline__ void gload16(const void* g, void* l) {
  // async global->LDS, 16B per lane; dest = (wave-uniform l) + lane*16
  __builtin_amdgcn_global_load_lds((const __attribute__((address_space(1))) void*)g,
                                   (__attribute__((address_space(3))) void*)l, 16, 0, 0);
}

// ---------------- conversion kernels ----------------

__global__ __launch_bounds__(256) void k_cvt_x(const float* __restrict__ in, u16* __restrict__ out) {
  size_t i = (size_t)blockIdx.x * 256 + threadIdx.x;
  const float4* p = (const float4*)in + i * 2;
  float4 a = p[0], b = p[1];
  u16x8 r;
  r[0] = f2bf(a.x); r[1] = f2bf(a.y); r[2] = f2bf(a.z); r[3] = f2bf(a.w);
  r[4] = f2bf(b.x); r[5] = f2bf(b.y); r[6] = f2bf(b.z); r[7] = f2bf(b.w);
  *(u16x8*)(out + i * 8) = r;
}

__global__ __launch_bounds__(256) void k_wtrans(const float* __restrict__ W0, const float* __restrict__ W1,
                                                const float* __restrict__ W2, const float* __restrict__ W3,
                                                u16* __restrict__ O0, u16* __restrict__ O1,
                                                u16* __restrict__ O2, u16* __restrict__ O3) {
  __shared__ float tile[64][65];
  const float* W = blockIdx.z == 0 ? W0 : blockIdx.z == 1 ? W1 : blockIdx.z == 2 ? W2 : W3;
  u16* O       = blockIdx.z == 0 ? O0 : blockIdx.z == 1 ? O1 : blockIdx.z == 2 ? O2 : O3;
  const int c0 = blockIdx.x * 64, r0 = blockIdx.y * 64;
  const int t = threadIdx.x;
  const int tr = t >> 4, tc = (t & 15) * 4;
#pragma unroll
  for (int p = 0; p < 4; p++) {
    int r = tr + p * 16;
    float4 v = *(const float4*)&W[(size_t)(r0 + r) * EMB + c0 + tc];
    tile[r][tc + 0] = v.x; tile[r][tc + 1] = v.y; tile[r][tc + 2] = v.z; tile[r][tc + 3] = v.w;
  }
  __syncthreads();
#pragma unroll
  for (int p = 0; p < 4; p++) {
    int orow = tr + p * 16;
    u16x4 o;
    o[0] = f2bf(tile[tc + 0][orow]); o[1] = f2bf(tile[tc + 1][orow]);
    o[2] = f2bf(tile[tc + 2][orow]); o[3] = f2bf(tile[tc + 3][orow]);
    *(u16x4*)&O[(size_t)(c0 + orow) * EMB + r0 + tc] = o;
  }
}

// ---------------- GEMM core: C(128x128) = A(Mx1024) * BT(Nx1024)^T ----------------
// Double-buffered LDS + counted vmcnt (T4): next tile's 8 gload_lds stay in flight
// across both raw s_barriers.

static __device__ __forceinline__ void gemm_core(const u16* __restrict__ A, const u16* __restrict__ BT,
                                                 int m0, int n0, f32x4 acc[4][4]) {
  __shared__ u16 As[2][128 * 64];
  __shared__ u16 Bs[2][128 * 64];
  const int t = threadIdx.x, l = t & 63, w = t >> 6;
  const int g = l >> 4, q = l & 15;
  const int wm = (w >> 1) * 64, wn = (w & 1) * 64;

  const f32x4 zero4 = {0.f, 0.f, 0.f, 0.f};
#pragma unroll
  for (int mi = 0; mi < 4; mi++)
#pragma unroll
    for (int ni = 0; ni < 4; ni++) acc[mi][ni] = zero4;

  int srow[4], skel[4];
#pragma unroll
  for (int i = 0; i < 4; i++) {
    int row = w * 32 + i * 8 + (l >> 3);
    srow[i] = row; skel[i] = ((l & 7) ^ (row & 7)) * 8;
  }

  auto stage = [&](int k0, int bsel) {
    char* AsB = (char*)As[bsel] + w * 4096;
    char* BsB = (char*)Bs[bsel] + w * 4096;
#pragma unroll
    for (int i = 0; i < 4; i++) {
      gload16(A + (size_t)(m0 + srow[i]) * EMB + k0 + skel[i], AsB + i * 1024);
      gload16(BT + (size_t)(n0 + srow[i]) * EMB + k0 + skel[i], BsB + i * 1024);
    }
  };

  auto compute = [&](int bsel) {
    char* AsB = (char*)As[bsel];
    char* BsB = (char*)Bs[bsel];
#pragma unroll
    for (int kc = 0; kc < 2; kc++) {
      bf16x8 af[4], bfv[4];
#pragma unroll
      for (int mi = 0; mi < 4; mi++) {
        int row = wm + mi * 16 + q;
        af[mi] = *(const bf16x8*)(AsB + row * 128 + (((kc * 4 + g) ^ (row & 7)) << 4));
      }
#pragma unroll
      for (int ni = 0; ni < 4; ni++) {
        int row = wn + ni * 16 + q;
        bfv[ni] = *(const bf16x8*)(BsB + row * 128 + (((kc * 4 + g) ^ (row & 7)) << 4));
      }
      __builtin_amdgcn_s_setprio(1);
#pragma unroll
      for (int mi = 0; mi < 4; mi++)
#pragma unroll
        for (int ni = 0; ni < 4; ni++)
          acc[mi][ni] = __builtin_amdgcn_mfma_f32_16x16x32_bf16(af[mi], bfv[ni], acc[mi][ni], 0, 0, 0);
      __builtin_amdgcn_s_setprio(0);
    }
  };

  stage(0, 0);                         // prologue: tile 0 in flight (8 loads)
  int buf = 0;
  for (int k0 = 64; k0 <= EMB; k0 += 64) {   // 16 iterations; iter j computes tile j
    const bool pf = (k0 < EMB);
    if (pf) {
      stage(k0, buf ^ 1);                            // +8 loads -> 16 outstanding
      asm volatile("s_waitcnt vmcnt(8)" ::: "memory");   // current tile landed; next stays in flight
    } else {
      asm volatile("s_waitcnt vmcnt(0)" ::: "memory");   // last tile: drain
    }
    __builtin_amdgcn_s_barrier();
    __builtin_amdgcn_sched_barrier(0);   // no ds_read hoisting above the barrier
    compute(buf);
    asm volatile("s_waitcnt lgkmcnt(0)" ::: "memory");
    __builtin_amdgcn_s_barrier();        // all waves done reading buf; safe to overwrite
    buf ^= 1;
  }
}

// Fused QKV projection: C(8192x3072) = xb * [WqT|WkT|WvT]^T.
__global__ __launch_bounds__(256) void k_gemm_qkv(const u16* __restrict__ xb, const u16* __restrict__ Wqkv,
                                                  u16* __restrict__ Qb, u16* __restrict__ Kb, u16* __restrict__ Vb) {
  const int wg = blockIdx.x;             // 1536 blocks = 64 m x 24 n
  const int c = wg & 7, local = wg >> 3; // XCD c owns n-panels [c*3, c*3+3)
  const int mi_ = local & 63, ni_ = c * 3 + (local >> 6);
  const int m0 = mi_ * 128, n0 = ni_ * 128;

  f32x4 acc[4][4];
  gemm_core(xb, Wqkv, m0, n0, acc);

  const int z = n0 >> 10;                // block-uniform: 0=Q 1=K 2=V
  u16* Out = z == 0 ? Qb : (z == 1 ? Kb : Vb);
  const float scale = z == 0 ? 0.125f * 1.4426950408889634f : 1.0f;   // fold 1/sqrt(D)*log2e into Q

  const int t = threadIdx.x, l = t & 63, w = t >> 6;
  const int g = l >> 4, q = l & 15;
  const int wm = (w >> 1) * 64, wn = (w & 1) * 64;
#pragma unroll
  for (int mi = 0; mi < 4; mi++)
#pragma unroll
    for (int ni = 0; ni < 4; ni++)
#pragma unroll
      for (int jj = 0; jj < 4; jj++) {
        int m = m0 + wm + mi * 16 + g * 4 + jj;
        int n = n0 + wn + ni * 16 + q;
        int b = m >> 11, s = m & 2047;
        int col = n & 1023;
        int h = col >> 6, d = col & 63;
        Out[(((size_t)(b * NHEAD + h)) * SEQ + s) * DHEAD + d] = f2bf(acc[mi][ni][jj] * scale);
      }
}

// Output projection: out(fp32) = Ob * Wo + bo. 512 = 64 m x 8 n; XCD c owns n-panel c.
__global__ __launch_bounds__(256) void k_gemm_out(const u16* __restrict__ Ob, const u16* __restrict__ WoT,
                                                  const float* __restrict__ bo, float* __restrict__ out) {
  const int wg = blockIdx.x;
  const int c = wg & 7, local = wg >> 3;
  const int m0 = (local & 63) * 128, n0 = c * 128;

  f32x4 acc[4][4];
  gemm_core(Ob, WoT, m0, n0, acc);

  const int t = threadIdx.x, l = t & 63, w = t >> 6;
  const int g = l >> 4, q = l & 15;
  const int wm = (w >> 1) * 64, wn = (w & 1) * 64;
#pragma unroll
  for (int ni = 0; ni < 4; ni++) {
    int n = n0 + wn + ni * 16 + q;
    float bv = bo[n];
#pragma unroll
    for (int mi = 0; mi < 4; mi++)
#pragma unroll
      for (int jj = 0; jj < 4; jj++) {
        int m = m0 + wm + mi * 16 + g * 4 + jj;
        out[(size_t)m * EMB + n] = acc[mi][ni][jj] + bv;
      }
  }
}

// ---------------- causal flash attention (merged-pair, zero-shuffle P->PV) ----------------
// grid (64 bh, 16); block 256 = 4 waves; q-tile pair (i, 31-i) shares one K/V stream.
// Key trick: V^T columns stored in permuted slot order sigma so each lane's QK^T
// outputs ARE its PV A-fragment (P never touches LDS; no cross-lane ops for P).
//   QK C/D: lane (g,q) holds key r = 16*kf + 4*g + jj  (K stored natural -> mask easy)
//   PV A-frag: lane (g,q) needs slot s = 32*kc + 8*g + j
//   sigma: s = 32*(kf>>1) + 8*g + 4*(kf&1) + jj  <->  r = 16*kf + 4*g + jj
// K/V-frags loaded once per k-tile, shared by both streams.
__global__ __launch_bounds__(256, 3) void k_attn(const u16* __restrict__ Qb, const u16* __restrict__ Kb,
                                                 const u16* __restrict__ Vb, u16* __restrict__ Ob) {
  __shared__ u16 Ks[2][64 * 64];    // [key][d], swizzled 16B chunks, natural key order
  __shared__ u16 Vt[2][64 * 64];    // [d][slot], swizzled 16B chunks, sigma slot order
  const int t = threadIdx.x, l = t & 63, w = t >> 6;
  const int g = l >> 4, q = l & 15;
  const int bh = blockIdx.x;
  const int b = bh >> 4, h = bh & 15;
  const size_t hb = (size_t)bh * SEQ * DHEAD;
  const float NEG_INF = -__builtin_inff();

  const int i = blockIdx.y;
  const int qA0 = i * 64, qB0 = (31 - i) * 64;
  const int ntA = i + 1, ntB = 32 - i;    // ntB >= 17 > ntA always

  int krow[2], kel[2];
#pragma unroll
  for (int ii = 0; ii < 2; ii++) {
    int row = w * 16 + ii * 8 + (l >> 3);
    krow[ii] = row; kel[ii] = ((l & 7) ^ (row & 7)) * 8;
  }
  const int kp = t & 31, d0v = (t >> 5) * 8;
  // sigma slot for this thread's key pair (r = 2*kp, 2*kp+1 -> slots sp, sp+1)
  const int r2 = 2 * kp;
  const int sp = 32 * ((r2 >> 4) >> 1) + 8 * ((r2 >> 2) & 3) + 4 * ((r2 >> 4) & 1) + (r2 & 3);

  auto stageK = [&](int kbase, int bsel) {
    char* dst = (char*)Ks[bsel] + w * 2048;
#pragma unroll
    for (int ii = 0; ii < 2; ii++)
      gload16(Kb + hb + (size_t)(kbase + krow[ii]) * DHEAD + kel[ii], dst + ii * 1024);
  };
  auto loadV = [&](int kbase, u16x8& v0, u16x8& v1) {
    v0 = *(const u16x8*)(Vb + hb + (size_t)(kbase + 2 * kp) * DHEAD + d0v);
    v1 = *(const u16x8*)(Vb + hb + (size_t)(kbase + 2 * kp + 1) * DHEAD + d0v);
  };
  auto writeV = [&](int bsel, const u16x8& v0, const u16x8& v1) {
    char* VtB = (char*)Vt[bsel];
#pragma unroll
    for (int ii = 0; ii < 8; ii++) {
      int d = d0v + ii;
      u32 val = (u32)v0[ii] | ((u32)v1[ii] << 16);
      *(u32*)(VtB + d * 128 + ((sp * 2) ^ ((d & 7) << 4))) = val;   // sigma column, <=2-way banks
    }
  };

  bf16x8 qfA[2], qfB[2];
#pragma unroll
  for (int kc = 0; kc < 2; kc++) {
    qfA[kc] = *(const bf16x8*)(Qb + hb + (size_t)(qA0 + w * 16 + q) * DHEAD + kc * 32 + g * 8);
    qfB[kc] = *(const bf16x8*)(Qb + hb + (size_t)(qB0 + w * 16 + q) * DHEAD + kc * 32 + g * 8);
  }
  const int qglobA = qA0 + w * 16 + q, qglobB = qB0 + w * 16 + q;

  f32x4 oA[4], oB[4];
  const f32x4 zero4 = {0.f, 0.f, 0.f, 0.f};
#pragma unroll
  for (int df = 0; df < 4; df++) { oA[df] = zero4; oB[df] = zero4; }
  float mA = NEG_INF, lA = 0.f, mB = NEG_INF, lB = 0.f;

  // QK^T for one stream using shared K-frags
  auto qk = [&](const bf16x8 (&kfr)[2][4], const bf16x8 (&qf)[2], f32x4 (&st)[4]) {
#pragma unroll
    for (int kf = 0; kf < 4; kf++) st[kf] = zero4;
    __builtin_amdgcn_s_setprio(1);
#pragma unroll
    for (int kc = 0; kc < 2; kc++)
#pragma unroll
      for (int kf = 0; kf < 4; kf++)
        st[kf] = __builtin_amdgcn_mfma_f32_16x16x32_bf16(kfr[kc][kf], qf[kc], st[kf], 0, 0, 0);
    __builtin_amdgcn_s_setprio(0);
  };

  // softmax for one stream; produces PV A-fragments in registers (zero shuffle)
  auto softmax_pa = [&](f32x4 (&st)[4], f32x4 (&o)[4], float& m_run, float& l_run,
                        bool diag, int qglob, int k0, bf16x8 (&pa)[2]) {
    if (diag) {
#pragma unroll
      for (int kf = 0; kf < 4; kf++)
#pragma unroll
        for (int jj = 0; jj < 4; jj++)
          if (k0 + kf * 16 + g * 4 + jj > qglob) st[kf][jj] = NEG_INF;
    }
    f32x4 mv;
#pragma unroll
    for (int jj = 0; jj < 4; jj++)
      mv[jj] = fmaxf(fmaxf(st[0][jj], st[1][jj]), fmaxf(st[2][jj], st[3][jj]));
    float smax = fmaxf(fmaxf(mv[0], mv[1]), fmaxf(mv[2], mv[3]));
    smax = fmaxf(smax, __shfl_xor(smax, 16));
    smax = fmaxf(smax, __shfl_xor(smax, 32));

    if (!__all(smax - m_run <= 8.0f)) {   // defer-max (log2 domain)
      float mnew = fmaxf(m_run, smax);
      float sc = fexp2(m_run - mnew);
      l_run *= sc;
#pragma unroll
      for (int jj = 0; jj < 4; jj++) {
        float scj = __shfl(sc, g * 4 + jj);
#pragma unroll
        for (int df = 0; df < 4; df++) o[df][jj] *= scj;
      }
      m_run = mnew;
    }

    f32x4 pv[4];
#pragma unroll
    for (int kf = 0; kf < 4; kf++)
#pragma unroll
      for (int jj = 0; jj < 4; jj++)
        pv[kf][jj] = fexp2(st[kf][jj] - m_run);
    f32x4 sv = (pv[0] + pv[1]) + (pv[2] + pv[3]);
    float psum = (sv[0] + sv[1]) + (sv[2] + sv[3]);
    psum += __shfl_xor(psum, 16);
    psum += __shfl_xor(psum, 32);
    l_run += psum;

    pa[0] = bf16x8{ (__bf16)pv[0][0], (__bf16)pv[0][1], (__bf16)pv[0][2], (__bf16)pv[0][3],
                    (__bf16)pv[1][0], (__bf16)pv[1][1], (__bf16)pv[1][2], (__bf16)pv[1][3] };
    pa[1] = bf16x8{ (__bf16)pv[2][0], (__bf16)pv[2][1], (__bf16)pv[2][2], (__bf16)pv[2][3],
                    (__bf16)pv[3][0], (__bf16)pv[3][1], (__bf16)pv[3][2], (__bf16)pv[3][3] };
  };

  auto pv_acc = [&](const bf16x8 (&pa)[2], const bf16x8 (&vfr)[2][4], f32x4 (&o)[4]) {
    __builtin_amdgcn_s_setprio(1);
#pragma unroll
    for (int kc = 0; kc < 2; kc++)
#pragma unroll
      for (int df = 0; df < 4; df++)
        o[df] = __builtin_amdgcn_mfma_f32_16x16x32_bf16(pa[kc], vfr[kc][df], o[df], 0, 0, 0);
    __builtin_amdgcn_s_setprio(0);
  };

  {  // prologue: stage tile 0
    u16x8 v0, v1;
    stageK(0, 0);
    loadV(0, v0, v1);
    writeV(0, v0, v1);
  }
  __syncthreads();

  int buf = 0;
  for (int kt = 0; kt < ntB; ++kt) {
    const int k0 = kt * 64;
    const bool pf = (kt + 1 < ntB);
    const bool actA = kt < ntA;
    u16x8 nv0, nv1;
    if (pf) {                              // prefetch next tile under compute
      stageK((kt + 1) * 64, buf ^ 1);
      loadV((kt + 1) * 64, nv0, nv1);
    }
    char* KsB = (char*)Ks[buf];
    char* VtB = (char*)Vt[buf];

    // shared K-frags -> QK for both streams
    bf16x8 kfr[2][4];
#pragma unroll
    for (int kc = 0; kc < 2; kc++)
#pragma unroll
      for (int kf = 0; kf < 4; kf++) {
        int key = kf * 16 + q;
        kfr[kc][kf] = *(const bf16x8*)(KsB + key * 128 + (((kc * 4 + g) ^ (key & 7)) << 4));
      }
    f32x4 stB[4], stA[4];
    qk(kfr, qfB, stB);
    if (actA) qk(kfr, qfA, stA);

    // shared V-frags
    bf16x8 vfr[2][4];
#pragma unroll
    for (int kc = 0; kc < 2; kc++)
#pragma unroll
      for (int df = 0; df < 4; df++) {
        int d = df * 16 + q;
        vfr[kc][df] = *(const bf16x8*)(VtB + d * 128 + (((kc * 4 + g) ^ (d & 7)) << 4));
      }

    bf16x8 paB[2], paA[2];
    softmax_pa(stB, oB, mB, lB, kt == ntB - 1, qglobB, k0, paB);
    pv_acc(paB, vfr, oB);
    if (actA) {
      softmax_pa(stA, oA, mA, lA, kt == ntA - 1, qglobA, k0, paA);
      pv_acc(paA, vfr, oA);
    }

    if (pf) writeV(buf ^ 1, nv0, nv1);   // land prefetched V
    __syncthreads();                     // drains gload_lds K + makes V visible
    buf ^= 1;
  }

  auto store = [&](f32x4 (&o)[4], float l_run, int q0) {
    float inv = 1.f / l_run;
#pragma unroll
    for (int jj = 0; jj < 4; jj++) {
      float r = __shfl(inv, g * 4 + jj);
      int s = q0 + w * 16 + g * 4 + jj;
#pragma unroll
      for (int df = 0; df < 4; df++)
        Ob[((size_t)(b * SEQ + s)) * EMB + h * DHEAD + df * 16 + q] = f2bf(o[df][jj] * r);
    }
  };
  store(oA, lA, qA0);
  store(oB, lB, qB0);
}

// ---------------- host ----------------

extern "C" void kernel_launch(void* const* d_in, const int* in_sizes, int n_in,
                              void* d_out, int out_size, void* d_ws, size_t ws_size,
                              hipStream_t stream) {
  const float* x  = (const float*)d_in[0];
  const float* Wq = (const float*)d_in[1];
  const float* Wk = (const float*)d_in[2];
  const float* Wv = (const float*)d_in[3];
  const float* Wo = (const float*)d_in[4];
  const float* bo = (const float*)d_in[5];
  float* out = (float*)d_out;

  char* ws = (char*)d_ws;
  u16* xb  = (u16*)(ws);                                   // 16 MB
  u16* WqT = (u16*)(ws + (16u << 20));                     // 2 MB each; Wq/Wk/Wv contiguous = fused B
  u16* WkT = WqT + (size_t)EMB * EMB;
  u16* WvT = WkT + (size_t)EMB * EMB;
  u16* WoT = WvT + (size_t)EMB * EMB;
  u16* Qb  = (u16*)(ws + (24u << 20));                     // 16 MB each
  u16* Kb  = Qb + (size_t)MTOT * EMB;
  u16* Vb  = Kb + (size_t)MTOT * EMB;
  u16* Ob  = Vb + (size_t)MTOT * EMB;                      // total 88 MB

  k_cvt_x<<<dim3(4096), 256, 0, stream>>>(x, xb);
  k_wtrans<<<dim3(16, 16, 4), 256, 0, stream>>>(Wq, Wk, Wv, Wo, WqT, WkT, WvT, WoT);
  k_gemm_qkv<<<dim3(1536), 256, 0, stream>>>(xb, WqT, Qb, Kb, Vb);
  k_attn<<<dim3(64, 16), 256, 0, stream>>>(Qb, Kb, Vb, Ob);
  k_gemm_out<<<dim3(512), 256, 0, stream>>>(Ob, WoT, bo, out);
}

// Round 7
// 171.704 us; speedup vs baseline: 1.0834x; 1.0834x over previous
//
#include <hip/hip_runtime.h>
#include <hip/hip_bf16.h>

typedef unsigned short u16;
typedef unsigned int u32;
typedef __bf16 bf16x8 __attribute__((ext_vector_type(8)));
typedef float f32x4 __attribute__((ext_vector_type(4)));
typedef u16 u16x8 __attribute__((ext_vector_type(8)));
typedef u16 u16x4 __attribute__((ext_vector_type(4)));

#define NB 4
#define SEQ 2048
#define EMB 1024
#define NHEAD 16
#define DHEAD 64
#define MTOT (NB*SEQ)   // 8192

static __device__ __forceinline__ u16 f2bf(float f) {
  union { __bf16 h; u16 u; } cv;
  cv.h = (__bf16)f;
  return cv.u;
}

static __device__ __forceinline__ float fexp2(float x) {
  float r;
  asm("v_exp_f32 %0, %1" : "=v"(r) : "v"(x));   // exp2, 1 instr, exp2(-inf)=0
  return r;
}

static __device__ __forceinline__ void gload16(const void* g, void* l) {
  // async global->LDS, 16B per lane; dest = (wave-uniform l) + lane*16
  __builtin_amdgcn_global_load_lds((const __attribute__((address_space(1))) void*)g,
                                   (__attribute__((address_space(3))) void*)l, 16, 0, 0);
}

// ---------------- conversion kernels ----------------

__global__ __launch_bounds__(256) void k_cvt_x(const float* __restrict__ in, u16* __restrict__ out) {
  size_t i = (size_t)blockIdx.x * 256 + threadIdx.x;
  const float4* p = (const float4*)in + i * 2;
  float4 a = p[0], b = p[1];
  u16x8 r;
  r[0] = f2bf(a.x); r[1] = f2bf(a.y); r[2] = f2bf(a.z); r[3] = f2bf(a.w);
  r[4] = f2bf(b.x); r[5] = f2bf(b.y); r[6] = f2bf(b.z); r[7] = f2bf(b.w);
  *(u16x8*)(out + i * 8) = r;
}

__global__ __launch_bounds__(256) void k_wtrans(const float* __restrict__ W0, const float* __restrict__ W1,
                                                const float* __restrict__ W2, const float* __restrict__ W3,
                                                u16* __restrict__ O0, u16* __restrict__ O1,
                                                u16* __restrict__ O2, u16* __restrict__ O3) {
  __shared__ float tile[64][65];
  const float* W = blockIdx.z == 0 ? W0 : blockIdx.z == 1 ? W1 : blockIdx.z == 2 ? W2 : W3;
  u16* O       = blockIdx.z == 0 ? O0 : blockIdx.z == 1 ? O1 : blockIdx.z == 2 ? O2 : O3;
  const int c0 = blockIdx.x * 64, r0 = blockIdx.y * 64;
  const int t = threadIdx.x;
  const int tr = t >> 4, tc = (t & 15) * 4;
#pragma unroll
  for (int p = 0; p < 4; p++) {
    int r = tr + p * 16;
    float4 v = *(const float4*)&W[(size_t)(r0 + r) * EMB + c0 + tc];
    tile[r][tc + 0] = v.x; tile[r][tc + 1] = v.y; tile[r][tc + 2] = v.z; tile[r][tc + 3] = v.w;
  }
  __syncthreads();
#pragma unroll
  for (int p = 0; p < 4; p++) {
    int orow = tr + p * 16;
    u16x4 o;
    o[0] = f2bf(tile[tc + 0][orow]); o[1] = f2bf(tile[tc + 1][orow]);
    o[2] = f2bf(tile[tc + 2][orow]); o[3] = f2bf(tile[tc + 3][orow]);
    *(u16x4*)&O[(size_t)(c0 + orow) * EMB + r0 + tc] = o;
  }
}

// ---------------- GEMM core: C(128x128) = A(Mx1024) * BT(Nx1024)^T ----------------
// Double-buffered LDS + counted vmcnt (T4): next tile's 8 gload_lds stay in flight
// across both raw s_barriers.

static __device__ __forceinline__ void gemm_core(const u16* __restrict__ A, const u16* __restrict__ BT,
                                                 int m0, int n0, f32x4 acc[4][4]) {
  __shared__ u16 As[2][128 * 64];
  __shared__ u16 Bs[2][128 * 64];
  const int t = threadIdx.x, l = t & 63, w = t >> 6;
  const int g = l >> 4, q = l & 15;
  const int wm = (w >> 1) * 64, wn = (w & 1) * 64;

  const f32x4 zero4 = {0.f, 0.f, 0.f, 0.f};
#pragma unroll
  for (int mi = 0; mi < 4; mi++)
#pragma unroll
    for (int ni = 0; ni < 4; ni++) acc[mi][ni] = zero4;

  int srow[4], skel[4];
#pragma unroll
  for (int i = 0; i < 4; i++) {
    int row = w * 32 + i * 8 + (l >> 3);
    srow[i] = row; skel[i] = ((l & 7) ^ (row & 7)) * 8;
  }

  auto stage = [&](int k0, int bsel) {
    char* AsB = (char*)As[bsel] + w * 4096;
    char* BsB = (char*)Bs[bsel] + w * 4096;
#pragma unroll
    for (int i = 0; i < 4; i++) {
      gload16(A + (size_t)(m0 + srow[i]) * EMB + k0 + skel[i], AsB + i * 1024);
      gload16(BT + (size_t)(n0 + srow[i]) * EMB + k0 + skel[i], BsB + i * 1024);
    }
  };

  auto compute = [&](int bsel) {
    char* AsB = (char*)As[bsel];
    char* BsB = (char*)Bs[bsel];
#pragma unroll
    for (int kc = 0; kc < 2; kc++) {
      bf16x8 af[4], bfv[4];
#pragma unroll
      for (int mi = 0; mi < 4; mi++) {
        int row = wm + mi * 16 + q;
        af[mi] = *(const bf16x8*)(AsB + row * 128 + (((kc * 4 + g) ^ (row & 7)) << 4));
      }
#pragma unroll
      for (int ni = 0; ni < 4; ni++) {
        int row = wn + ni * 16 + q;
        bfv[ni] = *(const bf16x8*)(BsB + row * 128 + (((kc * 4 + g) ^ (row & 7)) << 4));
      }
      __builtin_amdgcn_s_setprio(1);
#pragma unroll
      for (int mi = 0; mi < 4; mi++)
#pragma unroll
        for (int ni = 0; ni < 4; ni++)
          acc[mi][ni] = __builtin_amdgcn_mfma_f32_16x16x32_bf16(af[mi], bfv[ni], acc[mi][ni], 0, 0, 0);
      __builtin_amdgcn_s_setprio(0);
    }
  };

  stage(0, 0);                         // prologue: tile 0 in flight (8 loads)
  int buf = 0;
  for (int k0 = 64; k0 <= EMB; k0 += 64) {   // 16 iterations; iter j computes tile j
    const bool pf = (k0 < EMB);
    if (pf) {
      stage(k0, buf ^ 1);                            // +8 loads -> 16 outstanding
      asm volatile("s_waitcnt vmcnt(8)" ::: "memory");   // current tile landed; next stays in flight
    } else {
      asm volatile("s_waitcnt vmcnt(0)" ::: "memory");   // last tile: drain
    }
    __builtin_amdgcn_s_barrier();
    __builtin_amdgcn_sched_barrier(0);   // no ds_read hoisting above the barrier
    compute(buf);
    asm volatile("s_waitcnt lgkmcnt(0)" ::: "memory");
    __builtin_amdgcn_s_barrier();        // all waves done reading buf; safe to overwrite
    buf ^= 1;
  }
}

// Fused QKV projection: C(8192x3072) = xb * [WqT|WkT|WvT]^T.
__global__ __launch_bounds__(256) void k_gemm_qkv(const u16* __restrict__ xb, const u16* __restrict__ Wqkv,
                                                  u16* __restrict__ Qb, u16* __restrict__ Kb, u16* __restrict__ Vb) {
  const int wg = blockIdx.x;             // 1536 blocks = 64 m x 24 n
  const int c = wg & 7, local = wg >> 3; // XCD c owns n-panels [c*3, c*3+3)
  const int mi_ = local & 63, ni_ = c * 3 + (local >> 6);
  const int m0 = mi_ * 128, n0 = ni_ * 128;

  f32x4 acc[4][4];
  gemm_core(xb, Wqkv, m0, n0, acc);

  const int z = n0 >> 10;                // block-uniform: 0=Q 1=K 2=V
  u16* Out = z == 0 ? Qb : (z == 1 ? Kb : Vb);
  const float scale = z == 0 ? 0.125f * 1.4426950408889634f : 1.0f;   // fold 1/sqrt(D)*log2e into Q

  const int t = threadIdx.x, l = t & 63, w = t >> 6;
  const int g = l >> 4, q = l & 15;
  const int wm = (w >> 1) * 64, wn = (w & 1) * 64;
#pragma unroll
  for (int mi = 0; mi < 4; mi++)
#pragma unroll
    for (int ni = 0; ni < 4; ni++)
#pragma unroll
      for (int jj = 0; jj < 4; jj++) {
        int m = m0 + wm + mi * 16 + g * 4 + jj;
        int n = n0 + wn + ni * 16 + q;
        int b = m >> 11, s = m & 2047;
        int col = n & 1023;
        int h = col >> 6, d = col & 63;
        Out[(((size_t)(b * NHEAD + h)) * SEQ + s) * DHEAD + d] = f2bf(acc[mi][ni][jj] * scale);
      }
}

// Output projection: out(fp32) = Ob * Wo + bo. 512 = 64 m x 8 n; XCD c owns n-panel c.
__global__ __launch_bounds__(256) void k_gemm_out(const u16* __restrict__ Ob, const u16* __restrict__ WoT,
                                                  const float* __restrict__ bo, float* __restrict__ out) {
  const int wg = blockIdx.x;
  const int c = wg & 7, local = wg >> 3;
  const int m0 = (local & 63) * 128, n0 = c * 128;

  f32x4 acc[4][4];
  gemm_core(Ob, WoT, m0, n0, acc);

  const int t = threadIdx.x, l = t & 63, w = t >> 6;
  const int g = l >> 4, q = l & 15;
  const int wm = (w >> 1) * 64, wn = (w & 1) * 64;
#pragma unroll
  for (int ni = 0; ni < 4; ni++) {
    int n = n0 + wn + ni * 16 + q;
    float bv = bo[n];
#pragma unroll
    for (int mi = 0; mi < 4; mi++)
#pragma unroll
      for (int jj = 0; jj < 4; jj++) {
        int m = m0 + wm + mi * 16 + g * 4 + jj;
        out[(size_t)m * EMB + n] = acc[mi][ni][jj] + bv;
      }
  }
}

// ---------------- causal flash attention (merged-pair, zero-shuffle P, R5 schedule) ----------------
// grid (64 bh, 16); block 256 = 4 waves; q-tile pair (i, 31-i) shares one K/V stream.
// R5's per-stream compute structure (own ds_reads, fully independent chains) with the
// P-LDS round-trip deleted: V^T stored in sigma slot order so each lane's QK^T outputs
// ARE its PV A-fragment (in-register cvt; zero shuffles; zero P LDS; zero bank conflicts).
//   QK C/D: lane (g,q) holds key r = 16*kf + 4*g + jj
//   PV A-frag slot: s = 32*kc + 8*g + j;  sigma: s = 32*(kf>>1) + 8*g + 4*(kf&1) + jj
__global__ __launch_bounds__(256, 4) void k_attn(const u16* __restrict__ Qb, const u16* __restrict__ Kb,
                                                 const u16* __restrict__ Vb, u16* __restrict__ Ob) {
  __shared__ u16 Ks[2][64 * 64];    // [key][d], swizzled 16B chunks, natural key order
  __shared__ u16 Vt[2][64 * 64];    // [d][slot], swizzled 16B chunks, sigma slot order
  const int t = threadIdx.x, l = t & 63, w = t >> 6;
  const int g = l >> 4, q = l & 15;
  const int bh = blockIdx.x;
  const int b = bh >> 4, h = bh & 15;
  const size_t hb = (size_t)bh * SEQ * DHEAD;
  const float NEG_INF = -__builtin_inff();

  const int i = blockIdx.y;
  const int qA0 = i * 64, qB0 = (31 - i) * 64;
  const int ntA = i + 1, ntB = 32 - i;    // ntB >= 17 > ntA always

  int krow[2], kel[2];
#pragma unroll
  for (int ii = 0; ii < 2; ii++) {
    int row = w * 16 + ii * 8 + (l >> 3);
    krow[ii] = row; kel[ii] = ((l & 7) ^ (row & 7)) * 8;
  }
  const int kp = t & 31, d0v = (t >> 5) * 8;
  // sigma slot for this thread's key pair (r = 2*kp, 2*kp+1 -> slots sp, sp+1)
  const int r2 = 2 * kp;
  const int sp = 32 * ((r2 >> 4) >> 1) + 8 * ((r2 >> 2) & 3) + 4 * ((r2 >> 4) & 1) + (r2 & 3);

  auto stageK = [&](int kbase, int bsel) {
    char* dst = (char*)Ks[bsel] + w * 2048;
#pragma unroll
    for (int ii = 0; ii < 2; ii++)
      gload16(Kb + hb + (size_t)(kbase + krow[ii]) * DHEAD + kel[ii], dst + ii * 1024);
  };
  auto loadV = [&](int kbase, u16x8& v0, u16x8& v1) {
    v0 = *(const u16x8*)(Vb + hb + (size_t)(kbase + 2 * kp) * DHEAD + d0v);
    v1 = *(const u16x8*)(Vb + hb + (size_t)(kbase + 2 * kp + 1) * DHEAD + d0v);
  };
  auto writeV = [&](int bsel, const u16x8& v0, const u16x8& v1) {
    char* VtB = (char*)Vt[bsel];
#pragma unroll
    for (int ii = 0; ii < 8; ii++) {
      int d = d0v + ii;
      u32 val = (u32)v0[ii] | ((u32)v1[ii] << 16);
      *(u32*)(VtB + d * 128 + ((sp * 2) ^ ((d & 7) << 4))) = val;   // sigma column, <=2-way banks
    }
  };

  bf16x8 qfA[2], qfB[2];
#pragma unroll
  for (int kc = 0; kc < 2; kc++) {
    qfA[kc] = *(const bf16x8*)(Qb + hb + (size_t)(qA0 + w * 16 + q) * DHEAD + kc * 32 + g * 8);
    qfB[kc] = *(const bf16x8*)(Qb + hb + (size_t)(qB0 + w * 16 + q) * DHEAD + kc * 32 + g * 8);
  }
  const int qglobA = qA0 + w * 16 + q, qglobB = qB0 + w * 16 + q;

  f32x4 oA[4], oB[4];
  const f32x4 zero4 = {0.f, 0.f, 0.f, 0.f};
#pragma unroll
  for (int df = 0; df < 4; df++) { oA[df] = zero4; oB[df] = zero4; }
  float mA = NEG_INF, lA = 0.f, mB = NEG_INF, lB = 0.f;

  // one k-tile compute for one stream (R5 structure: own ds_reads; P in registers)
  auto compute = [&](const bf16x8 (&qf)[2], f32x4 (&o)[4], float& m_run, float& l_run,
                     bool diag, int qglob, int k0, char* KsB, char* VtB) {
    // S^T[key][q] = K * Q^T (exp2 domain)
    f32x4 st[4];
#pragma unroll
    for (int kf = 0; kf < 4; kf++) st[kf] = zero4;
    __builtin_amdgcn_s_setprio(1);
#pragma unroll
    for (int kc = 0; kc < 2; kc++)
#pragma unroll
      for (int kf = 0; kf < 4; kf++) {
        int key = kf * 16 + q;
        bf16x8 a = *(const bf16x8*)(KsB + key * 128 + (((kc * 4 + g) ^ (key & 7)) << 4));
        st[kf] = __builtin_amdgcn_mfma_f32_16x16x32_bf16(a, qf[kc], st[kf], 0, 0, 0);
      }
    __builtin_amdgcn_s_setprio(0);

    if (diag) {
#pragma unroll
      for (int kf = 0; kf < 4; kf++)
#pragma unroll
        for (int jj = 0; jj < 4; jj++)
          if (k0 + kf * 16 + g * 4 + jj > qglob) st[kf][jj] = NEG_INF;
    }

    f32x4 mv;
#pragma unroll
    for (int jj = 0; jj < 4; jj++)
      mv[jj] = fmaxf(fmaxf(st[0][jj], st[1][jj]), fmaxf(st[2][jj], st[3][jj]));
    float smax = fmaxf(fmaxf(mv[0], mv[1]), fmaxf(mv[2], mv[3]));
    smax = fmaxf(smax, __shfl_xor(smax, 16));
    smax = fmaxf(smax, __shfl_xor(smax, 32));

    if (!__all(smax - m_run <= 8.0f)) {   // defer-max (log2 domain)
      float mnew = fmaxf(m_run, smax);
      float sc = fexp2(m_run - mnew);
      l_run *= sc;
#pragma unroll
      for (int jj = 0; jj < 4; jj++) {
        float scj = __shfl(sc, g * 4 + jj);
#pragma unroll
        for (int df = 0; df < 4; df++) o[df][jj] *= scj;
      }
      m_run = mnew;
    }

    f32x4 pv[4];
#pragma unroll
    for (int kf = 0; kf < 4; kf++)
#pragma unroll
      for (int jj = 0; jj < 4; jj++)
        pv[kf][jj] = fexp2(st[kf][jj] - m_run);
    f32x4 sv = (pv[0] + pv[1]) + (pv[2] + pv[3]);
    float psum = (sv[0] + sv[1]) + (sv[2] + sv[3]);
    psum += __shfl_xor(psum, 16);
    psum += __shfl_xor(psum, 32);
    l_run += psum;

    // P -> PV A-fragments entirely in registers (sigma V layout makes this exact)
    bf16x8 pa[2];
    pa[0] = bf16x8{ (__bf16)pv[0][0], (__bf16)pv[0][1], (__bf16)pv[0][2], (__bf16)pv[0][3],
                    (__bf16)pv[1][0], (__bf16)pv[1][1], (__bf16)pv[1][2], (__bf16)pv[1][3] };
    pa[1] = bf16x8{ (__bf16)pv[2][0], (__bf16)pv[2][1], (__bf16)pv[2][2], (__bf16)pv[2][3],
                    (__bf16)pv[3][0], (__bf16)pv[3][1], (__bf16)pv[3][2], (__bf16)pv[3][3] };

    // O += P * V
    __builtin_amdgcn_s_setprio(1);
#pragma unroll
    for (int kc = 0; kc < 2; kc++) {
#pragma unroll
      for (int df = 0; df < 4; df++) {
        int d = df * 16 + q;
        bf16x8 vb = *(const bf16x8*)(VtB + d * 128 + (((kc * 4 + g) ^ (d & 7)) << 4));
        o[df] = __builtin_amdgcn_mfma_f32_16x16x32_bf16(pa[kc], vb, o[df], 0, 0, 0);
      }
    }
    __builtin_amdgcn_s_setprio(0);
  };

  {  // prologue: stage tile 0
    u16x8 v0, v1;
    stageK(0, 0);
    loadV(0, v0, v1);
    writeV(0, v0, v1);
  }
  __syncthreads();

  int buf = 0;
  for (int kt = 0; kt < ntB; ++kt) {
    const int k0 = kt * 64;
    const bool pf = (kt + 1 < ntB);
    u16x8 nv0, nv1;
    if (pf) {                              // prefetch next tile under compute
      stageK((kt + 1) * 64, buf ^ 1);
      loadV((kt + 1) * 64, nv0, nv1);
    }
    char* KsB = (char*)Ks[buf];
    char* VtB = (char*)Vt[buf];

    compute(qfB, oB, mB, lB, kt == ntB - 1, qglobB, k0, KsB, VtB);
    __builtin_amdgcn_sched_barrier(0);     // keep the two stream chains separate (R5 behavior)
    if (kt < ntA)
      compute(qfA, oA, mA, lA, kt == ntA - 1, qglobA, k0, KsB, VtB);

    if (pf) writeV(buf ^ 1, nv0, nv1);     // land prefetched V
    __syncthreads();                       // drains gload_lds K + makes V visible
    buf ^= 1;
  }

  auto store = [&](f32x4 (&o)[4], float l_run, int q0) {
    float inv = 1.f / l_run;
#pragma unroll
    for (int jj = 0; jj < 4; jj++) {
      float r = __shfl(inv, g * 4 + jj);
      int s = q0 + w * 16 + g * 4 + jj;
#pragma unroll
      for (int df = 0; df < 4; df++)
        Ob[((size_t)(b * SEQ + s)) * EMB + h * DHEAD + df * 16 + q] = f2bf(o[df][jj] * r);
    }
  };
  store(oA, lA, qA0);
  store(oB, lB, qB0);
}

// ---------------- host ----------------

extern "C" void kernel_launch(void* const* d_in, const int* in_sizes, int n_in,
                              void* d_out, int out_size, void* d_ws, size_t ws_size,
                              hipStream_t stream) {
  const float* x  = (const float*)d_in[0];
  const float* Wq = (const float*)d_in[1];
  const float* Wk = (const float*)d_in[2];
  const float* Wv = (const float*)d_in[3];
  const float* Wo = (const float*)d_in[4];
  const float* bo = (const float*)d_in[5];
  float* out = (float*)d_out;

  char* ws = (char*)d_ws;
  u16* xb  = (u16*)(ws);                                   // 16 MB
  u16* WqT = (u16*)(ws + (16u << 20));                     // 2 MB each; Wq/Wk/Wv contiguous = fused B
  u16* WkT = WqT + (size_t)EMB * EMB;
  u16* WvT = WkT + (size_t)EMB * EMB;
  u16* WoT = WvT + (size_t)EMB * EMB;
  u16* Qb  = (u16*)(ws + (24u << 20));                     // 16 MB each
  u16* Kb  = Qb + (size_t)MTOT * EMB;
  u16* Vb  = Kb + (size_t)MTOT * EMB;
  u16* Ob  = Vb + (size_t)MTOT * EMB;                      // total 88 MB

  k_cvt_x<<<dim3(4096), 256, 0, stream>>>(x, xb);
  k_wtrans<<<dim3(16, 16, 4), 256, 0, stream>>>(Wq, Wk, Wv, Wo, WqT, WkT, WvT, WoT);
  k_gemm_qkv<<<dim3(1536), 256, 0, stream>>>(xb, WqT, Qb, Kb, Vb);
  k_attn<<<dim3(64, 16), 256, 0, stream>>>(Qb, Kb, Vb, Ob);
  k_gemm_out<<<dim3(512), 256, 0, stream>>>(Ob, WoT, bo, out);
}